// Round 3
// baseline (378.802 us; speedup 1.0000x reference)
//
#include <hip/hip_runtime.h>
#include <hip/hip_bf16.h>

// NeighbourhoodAttnBlock: B=2, H=W=64, D=512, NH=8, DH=64, KERNEL=7
// Inputs fp32; output fp32 (reference dtypes). Internal pipeline bf16 MFMA.
// Stage 0: convert x, w_qkv, w_out fp32 -> bf16 in ws
// Stage 1: qkv = x @ w_qkv^T  -> scatter to q/k/v [B,NH,S,DH] bf16
// Stage 2: neighbourhood attention, 49 keys per query (clamped 7x7 window)
// Stage 3: out = attn_out @ w_out^T -> d_out (fp32)

typedef __bf16 bf16x8 __attribute__((ext_vector_type(8)));
typedef __bf16 bf16x4 __attribute__((ext_vector_type(4)));
typedef float  f32x4  __attribute__((ext_vector_type(4)));

__global__ __launch_bounds__(256) void cvt_f32_bf16(
    const float* __restrict__ src, __bf16* __restrict__ dst, int n4) {
  int i = blockIdx.x * blockDim.x + threadIdx.x;
  if (i < n4) {
    f32x4 v = ((const f32x4*)src)[i];
    bf16x4 o;
    o[0] = (__bf16)v[0]; o[1] = (__bf16)v[1];
    o[2] = (__bf16)v[2]; o[3] = (__bf16)v[3];
    ((bf16x4*)dst)[i] = o;
  }
}

// C[i][e] = sum_d A[i][d] * W[e][d];  A:[M,K], W:[E,K] row-major bf16.
// One wave computes a 32x32 output tile with 4x mfma_f32_16x16x32_bf16.
// A/B frag [m|n=lane&15][k=(lane>>4)*8+j]; C/D: col(n)=lane&15,
// row(m)=(lane>>4)*4+reg.  (verified layouts per guide m89/m92)
template <int K, bool QKV>
__global__ __launch_bounds__(256) void gemm_bt(
    const __bf16* __restrict__ A, const __bf16* __restrict__ W,
    __bf16* __restrict__ qo, __bf16* __restrict__ ko, __bf16* __restrict__ vo,
    float* __restrict__ co, int etiles) {
  const int wave = (blockIdx.x << 2) | (threadIdx.x >> 6);
  const int lane = threadIdx.x & 63;
  const int it = wave / etiles, et = wave % etiles;
  const int i0 = it << 5, e0 = et << 5;
  const int r = lane & 15, q4 = lane >> 4;

  const __bf16* ap0 = A + (size_t)(i0 + r) * K + q4 * 8;
  const __bf16* ap1 = ap0 + (size_t)16 * K;
  const __bf16* bp0 = W + (size_t)(e0 + r) * K + q4 * 8;
  const __bf16* bp1 = bp0 + (size_t)16 * K;

  f32x4 acc00 = {0.f, 0.f, 0.f, 0.f};
  f32x4 acc01 = acc00, acc10 = acc00, acc11 = acc00;

#pragma unroll 4
  for (int k0 = 0; k0 < K; k0 += 32) {
    bf16x8 a0 = *(const bf16x8*)(ap0 + k0);
    bf16x8 a1 = *(const bf16x8*)(ap1 + k0);
    bf16x8 b0 = *(const bf16x8*)(bp0 + k0);
    bf16x8 b1 = *(const bf16x8*)(bp1 + k0);
    acc00 = __builtin_amdgcn_mfma_f32_16x16x32_bf16(a0, b0, acc00, 0, 0, 0);
    acc01 = __builtin_amdgcn_mfma_f32_16x16x32_bf16(a0, b1, acc01, 0, 0, 0);
    acc10 = __builtin_amdgcn_mfma_f32_16x16x32_bf16(a1, b0, acc10, 0, 0, 0);
    acc11 = __builtin_amdgcn_mfma_f32_16x16x32_bf16(a1, b1, acc11, 0, 0, 0);
  }

  const int row = (lane >> 4) << 2, col = lane & 15;
  f32x4 accs[2][2] = {{acc00, acc01}, {acc10, acc11}};
#pragma unroll
  for (int di = 0; di < 2; ++di) {
#pragma unroll
    for (int de = 0; de < 2; ++de) {
      f32x4 f = accs[di][de];
      int e = e0 + de * 16 + col;
#pragma unroll
      for (int rg = 0; rg < 4; ++rg) {
        int i = i0 + di * 16 + row + rg;
        float val = f[rg];
        if (QKV) {
          // channel e = t*512 + head*64 + dh (reference reshape order)
          int t = e >> 9, head = (e >> 6) & 7, dh = e & 63;
          int b = i >> 12, s = i & 4095;
          size_t off = (((size_t)(b * 8 + head) * 4096) + s) * 64 + dh;
          __bf16* dst = (t == 0) ? qo : ((t == 1) ? ko : vo);
          dst[off] = (__bf16)val;
        } else {
          co[(size_t)i * 512 + e] = val;  // fp32 output
        }
      }
    }
  }
}

// One wave per (b, head, query). Lane=key for scores/softmax (49 of 64 lanes),
// lane=dh for PV. q/k/v: [B,NH,S,DH] bf16. out: [B,S, NH*DH] bf16.
__global__ __launch_bounds__(256) void attn_kernel(
    const __bf16* __restrict__ q, const __bf16* __restrict__ k,
    const __bf16* __restrict__ v, __bf16* __restrict__ out) {
  __shared__ float qs[4][64];
  const int wv = threadIdx.x >> 6;
  const int lane = threadIdx.x & 63;
  const int gid = (blockIdx.x << 2) | wv;  // 0..65535
  const int s = gid & 4095;
  const int head = (gid >> 12) & 7;
  const int b = gid >> 15;
  const int hh = s >> 6, wcol = s & 63;
  int sh = hh - 3; sh = sh < 0 ? 0 : (sh > 57 ? 57 : sh);
  int sw = wcol - 3; sw = sw < 0 ? 0 : (sw > 57 ? 57 : sw);

  const size_t headbase = ((size_t)(b * 8 + head)) * 4096 * 64;
  const __bf16* qrow = q + headbase + (size_t)s * 64;
  qs[wv][lane] = (float)qrow[lane];
  __syncthreads();

  // --- scores: lane = key index (0..48 valid) ---
  const int kk = (lane < 49) ? lane : 0;
  const int ks = (sh + kk / 7) * 64 + (sw + kk % 7);
  const __bf16* krow = k + headbase + (size_t)ks * 64;
  float sc = 0.f;
#pragma unroll
  for (int j = 0; j < 64; j += 8) {
    bf16x8 kv = *(const bf16x8*)(krow + j);
#pragma unroll
    for (int t = 0; t < 8; ++t) sc += qs[wv][j + t] * (float)kv[t];
  }
  sc *= 0.125f;  // D_HEAD^-0.5
  if (lane >= 49) sc = -1e30f;

  // --- softmax across the wave ---
  float m = sc;
#pragma unroll
  for (int off = 32; off >= 1; off >>= 1) {
    float o = __shfl_xor(m, off);
    m = m > o ? m : o;
  }
  float p = __expf(sc - m);
  float sum = p;
#pragma unroll
  for (int off = 32; off >= 1; off >>= 1) sum += __shfl_xor(sum, off);
  p /= sum;

  // --- PV: lane = dh ---
  const __bf16* vb = v + headbase;
  float acc = 0.f;
  for (int key = 0; key < 49; ++key) {
    float pk = __shfl(p, key);
    int kr = (sh + key / 7) * 64 + (sw + key % 7);  // wave-uniform
    acc += pk * (float)vb[(size_t)kr * 64 + lane];
  }
  // out channel d = head*64 + dh  (reference transpose(0,2,1,3) order)
  out[((size_t)(b * 4096 + s)) * 512 + head * 64 + lane] = (__bf16)acc;
}

extern "C" void kernel_launch(void* const* d_in, const int* in_sizes, int n_in,
                              void* d_out, int out_size, void* d_ws,
                              size_t ws_size, hipStream_t stream) {
  const float* x = (const float*)d_in[0];      // [2,64,64,512] fp32
  const float* w_qkv = (const float*)d_in[1];  // [1536,512] fp32
  const float* w_out = (const float*)d_in[2];  // [512,512] fp32
  float* out = (float*)d_out;                  // [2,64,64,512] fp32

  const size_t qelems = (size_t)2 * 8 * 4096 * 64;  // 4,194,304
  __bf16* q = (__bf16*)d_ws;
  __bf16* k = q + qelems;
  __bf16* v = k + qelems;
  __bf16* xb = v + qelems;          // converted x [8192,512]; reused as ao
  __bf16* wqb = xb + qelems;        // converted w_qkv [1536,512]
  __bf16* wob = wqb + 1536 * 512;   // converted w_out [512,512]
  __bf16* ao = xb;                  // attn out aliases xb (x dead after QKV GEMM)
  // total ws: 4*8.39MB + 1.5MB + 0.5MB ~= 35.6 MB

  // Stage 0: fp32 -> bf16 conversions (vectorized x4)
  cvt_f32_bf16<<<dim3((int)(qelems / 4 / 256)), dim3(256), 0, stream>>>(
      x, xb, (int)(qelems / 4));
  cvt_f32_bf16<<<dim3(768), dim3(256), 0, stream>>>(w_qkv, wqb, 1536 * 512 / 4);
  cvt_f32_bf16<<<dim3(256), dim3(256), 0, stream>>>(w_out, wob, 512 * 512 / 4);

  // Stage 1: QKV GEMM: M=8192 (256 i-tiles), E=1536 (48 e-tiles) -> 12288 waves
  gemm_bt<512, true><<<dim3(3072), dim3(256), 0, stream>>>(
      xb, wqb, q, k, v, nullptr, 48);
  // Stage 2: attention: 2*8*4096 = 65536 query-heads, 4 waves/block
  attn_kernel<<<dim3(16384), dim3(256), 0, stream>>>(q, k, v, ao);
  // Stage 3: out GEMM: M=8192, E=512 (16 e-tiles) -> 4096 waves
  gemm_bt<512, false><<<dim3(1024), dim3(256), 0, stream>>>(
      ao, wob, nullptr, nullptr, nullptr, out, 16);
}

// Round 4
// 238.813 us; speedup vs baseline: 1.5862x; 1.5862x over previous
//
#include <hip/hip_runtime.h>
#include <hip/hip_bf16.h>

// NeighbourhoodAttnBlock: B=2, H=W=64, D=512, NH=8, DH=64, KERNEL=7
// Inputs fp32; output fp32. Internal pipeline bf16 MFMA.
// Stage 0: convert x, w_qkv, w_out fp32 -> bf16 in ws
// Stage 1: qkv GEMM -> q,k [bh][s][dh]; v transposed -> vt [bh][dh][s]
// Stage 2: MFMA neighbourhood attention, one workgroup per (bh, 8x8 query tile)
// Stage 3: out = attn_out @ w_out^T -> d_out (fp32)

typedef __bf16 bf16x8 __attribute__((ext_vector_type(8)));
typedef __bf16 bf16x4 __attribute__((ext_vector_type(4)));
typedef float  f32x4  __attribute__((ext_vector_type(4)));

__global__ __launch_bounds__(256) void cvt_f32_bf16(
    const float* __restrict__ src, __bf16* __restrict__ dst, int n4) {
  int i = blockIdx.x * blockDim.x + threadIdx.x;
  if (i < n4) {
    f32x4 v = ((const f32x4*)src)[i];
    bf16x4 o;
    o[0] = (__bf16)v[0]; o[1] = (__bf16)v[1];
    o[2] = (__bf16)v[2]; o[3] = (__bf16)v[3];
    ((bf16x4*)dst)[i] = o;
  }
}

// C[i][e] = sum_d A[i][d] * W[e][d];  A:[M,K], W:[E,K] row-major bf16.
// One wave = 32x32 tile, 4x mfma_f32_16x16x32_bf16.
// A/B frag [m|n=lane&15][k=(lane>>4)*8+j]; C/D: col(n)=lane&15,
// row(m)=(lane>>4)*4+reg.
template <int K, bool QKV>
__global__ __launch_bounds__(256) void gemm_bt(
    const __bf16* __restrict__ A, const __bf16* __restrict__ W,
    __bf16* __restrict__ qo, __bf16* __restrict__ ko, __bf16* __restrict__ vo,
    float* __restrict__ co, int etiles) {
  const int wave = (blockIdx.x << 2) | (threadIdx.x >> 6);
  const int lane = threadIdx.x & 63;
  const int it = wave / etiles, et = wave % etiles;
  const int i0 = it << 5, e0 = et << 5;
  const int r = lane & 15, q4 = lane >> 4;

  const __bf16* ap0 = A + (size_t)(i0 + r) * K + q4 * 8;
  const __bf16* ap1 = ap0 + (size_t)16 * K;
  const __bf16* bp0 = W + (size_t)(e0 + r) * K + q4 * 8;
  const __bf16* bp1 = bp0 + (size_t)16 * K;

  f32x4 acc00 = {0.f, 0.f, 0.f, 0.f};
  f32x4 acc01 = acc00, acc10 = acc00, acc11 = acc00;

#pragma unroll 4
  for (int k0 = 0; k0 < K; k0 += 32) {
    bf16x8 a0 = *(const bf16x8*)(ap0 + k0);
    bf16x8 a1 = *(const bf16x8*)(ap1 + k0);
    bf16x8 b0 = *(const bf16x8*)(bp0 + k0);
    bf16x8 b1 = *(const bf16x8*)(bp1 + k0);
    acc00 = __builtin_amdgcn_mfma_f32_16x16x32_bf16(a0, b0, acc00, 0, 0, 0);
    acc01 = __builtin_amdgcn_mfma_f32_16x16x32_bf16(a0, b1, acc01, 0, 0, 0);
    acc10 = __builtin_amdgcn_mfma_f32_16x16x32_bf16(a1, b0, acc10, 0, 0, 0);
    acc11 = __builtin_amdgcn_mfma_f32_16x16x32_bf16(a1, b1, acc11, 0, 0, 0);
  }

  const int row = (lane >> 4) << 2, col = lane & 15;
  f32x4 accs[2][2] = {{acc00, acc01}, {acc10, acc11}};
#pragma unroll
  for (int di = 0; di < 2; ++di) {
#pragma unroll
    for (int de = 0; de < 2; ++de) {
      f32x4 f = accs[di][de];
      int e = e0 + de * 16 + col;
#pragma unroll
      for (int rg = 0; rg < 4; ++rg) {
        int i = i0 + di * 16 + row + rg;
        float val = f[rg];
        if (QKV) {
          int t = e >> 9, head = (e >> 6) & 7, dh = e & 63;
          int b = i >> 12, s = i & 4095;
          int bh = b * 8 + head;
          if (t == 2) {
            // V stored transposed: vt[bh][dh][s]
            vo[((size_t)bh * 64 + dh) * 4096 + s] = (__bf16)val;
          } else {
            size_t off = (((size_t)bh * 4096) + s) * 64 + dh;
            ((t == 0) ? qo : ko)[off] = (__bf16)val;
          }
        } else {
          co[(size_t)i * 512 + e] = val;  // fp32 output
        }
      }
    }
  }
}

// MFMA neighbourhood attention. One workgroup per (bh, 8x8 query tile).
// Wave wv handles queries [wv*16, wv*16+16) of the 64-query tile.
// Key window: 14 rows x 16 cols (wh0/wc0 clamped; wc0 multiple of 4),
// 224 keys; invalid keys masked exactly per query.
__global__ __launch_bounds__(256) void attn_mfma(
    const __bf16* __restrict__ q, const __bf16* __restrict__ k,
    const __bf16* __restrict__ vt, __bf16* __restrict__ out) {
  __shared__ alignas(16) __bf16 plds[4][16][232];  // per-wave P, +8 pad
  const int wv = threadIdx.x >> 6;
  const int lane = threadIdx.x & 63;
  const int n16 = lane & 15, quad = lane >> 4;
  const int bh = blockIdx.x >> 6;
  const int tile = blockIdx.x & 63;
  const int qh0 = (tile >> 3) << 3, qw0 = (tile & 7) << 3;
  int wh0 = qh0 - 3; wh0 = wh0 < 0 ? 0 : (wh0 > 50 ? 50 : wh0);
  int wc0 = qw0 - 3; wc0 = wc0 < 0 ? 0 : (wc0 > 48 ? 48 : wc0);
  wc0 &= ~1;  // even start: covers [qw0-3, qw0+10], keeps V loads 4B-aligned
  const size_t base = (size_t)bh * 4096 * 64;

  // ---- Q A-frags (2 k-steps over dh=64) ----
  const int qi_a = wv * 16 + n16;
  const int sqa = (qh0 + (qi_a >> 3)) * 64 + qw0 + (qi_a & 7);
  const __bf16* qp = q + base + (size_t)sqa * 64 + quad * 8;
  bf16x8 aq0 = *(const bf16x8*)qp;
  bf16x8 aq1 = *(const bf16x8*)(qp + 32);

  // ---- scores: S[nt] = Q . K_row(nt)^T, nt = window row 0..13 ----
  f32x4 S[14];
  const int skw = wc0 + n16;  // this lane's key col (B-frag n)
#pragma unroll
  for (int nt = 0; nt < 14; ++nt) {
    const __bf16* kp =
        k + base + (size_t)((wh0 + nt) * 64 + skw) * 64 + quad * 8;
    bf16x8 b0 = *(const bf16x8*)kp;
    bf16x8 b1 = *(const bf16x8*)(kp + 32);
    f32x4 s = {0.f, 0.f, 0.f, 0.f};
    s = __builtin_amdgcn_mfma_f32_16x16x32_bf16(aq0, b0, s, 0, 0, 0);
    s = __builtin_amdgcn_mfma_f32_16x16x32_bf16(aq1, b1, s, 0, 0, 0);
    S[nt] = s;
  }

  // ---- exact mask + scale + row max (rows live in 16-lane groups) ----
  float mx[4] = {-1e30f, -1e30f, -1e30f, -1e30f};
#pragma unroll
  for (int reg = 0; reg < 4; ++reg) {
    int qi = wv * 16 + quad * 4 + reg;
    int qh = qh0 + (qi >> 3), qw = qw0 + (qi & 7);
    int sh = qh - 3; sh = sh < 0 ? 0 : (sh > 57 ? 57 : sh);
    int sw = qw - 3; sw = sw < 0 ? 0 : (sw > 57 ? 57 : sw);
    bool wok = (skw >= sw) && (skw < sw + 7);
#pragma unroll
    for (int nt = 0; nt < 14; ++nt) {
      int kh = wh0 + nt;
      bool ok = wok && (kh >= sh) && (kh < sh + 7);
      float val = ok ? S[nt][reg] * 0.125f : -1e30f;
      S[nt][reg] = val;
      mx[reg] = mx[reg] > val ? mx[reg] : val;
    }
  }
#pragma unroll
  for (int reg = 0; reg < 4; ++reg)
#pragma unroll
    for (int off = 8; off >= 1; off >>= 1) {
      float o = __shfl_xor(mx[reg], off);
      mx[reg] = mx[reg] > o ? mx[reg] : o;
    }

  // ---- exp + row sum ----
  float sm[4] = {0.f, 0.f, 0.f, 0.f};
#pragma unroll
  for (int nt = 0; nt < 14; ++nt)
#pragma unroll
    for (int reg = 0; reg < 4; ++reg) {
      float p = __expf(S[nt][reg] - mx[reg]);
      S[nt][reg] = p;
      sm[reg] += p;
    }
#pragma unroll
  for (int reg = 0; reg < 4; ++reg)
#pragma unroll
    for (int off = 8; off >= 1; off >>= 1) sm[reg] += __shfl_xor(sm[reg], off);

  // ---- P -> LDS (bf16, C-layout scatter), wave-private so no barrier ----
#pragma unroll
  for (int reg = 0; reg < 4; ++reg) {
    float inv = 1.f / sm[reg];
    int row = quad * 4 + reg;
#pragma unroll
    for (int nt = 0; nt < 14; ++nt)
      plds[wv][row][nt * 16 + n16] = (__bf16)(S[nt][reg] * inv);
  }

  // ---- PV: O[16q x 64dh] = P(16x224) . V_win(224x64) ----
  f32x4 O[4] = {{0.f, 0.f, 0.f, 0.f},
                {0.f, 0.f, 0.f, 0.f},
                {0.f, 0.f, 0.f, 0.f},
                {0.f, 0.f, 0.f, 0.f}};
#pragma unroll
  for (int kt = 0; kt < 7; ++kt) {
    // A-frag from LDS: row = query (lane&15), k = kt*32+quad*8+j
    bf16x8 pa = *(const bf16x8*)&plds[wv][n16][kt * 32 + quad * 8];
    // B-frag from vt: n = dh, k = key; 8 consecutive keys = 8 consecutive s
    int key0 = kt * 32 + quad * 8;
    int sv = (wh0 + (key0 >> 4)) * 64 + wc0 + (key0 & 15);
#pragma unroll
    for (int ntv = 0; ntv < 4; ++ntv) {
      const __bf16* vp = vt + base + (size_t)(ntv * 16 + n16) * 4096 + sv;
      union { bf16x8 v8; bf16x4 v4[2]; } u;
      u.v4[0] = *(const bf16x4*)vp;        // sv % 4 == 0 -> 8B aligned
      u.v4[1] = *(const bf16x4*)(vp + 4);
      O[ntv] = __builtin_amdgcn_mfma_f32_16x16x32_bf16(pa, u.v8, O[ntv], 0, 0, 0);
    }
  }

  // ---- epilogue: out[b][s][head*64+dh] bf16 ----
  const int b = bh >> 3, head = bh & 7;
#pragma unroll
  for (int ntv = 0; ntv < 4; ++ntv)
#pragma unroll
    for (int reg = 0; reg < 4; ++reg) {
      int qi = wv * 16 + quad * 4 + reg;
      int s_q = (qh0 + (qi >> 3)) * 64 + qw0 + (qi & 7);
      int dh = ntv * 16 + n16;
      out[((size_t)(b * 4096 + s_q)) * 512 + head * 64 + dh] =
          (__bf16)O[ntv][reg];
    }
}

extern "C" void kernel_launch(void* const* d_in, const int* in_sizes, int n_in,
                              void* d_out, int out_size, void* d_ws,
                              size_t ws_size, hipStream_t stream) {
  const float* x = (const float*)d_in[0];      // [2,64,64,512] fp32
  const float* w_qkv = (const float*)d_in[1];  // [1536,512] fp32
  const float* w_out = (const float*)d_in[2];  // [512,512] fp32
  float* out = (float*)d_out;                  // [2,64,64,512] fp32

  const size_t qelems = (size_t)2 * 8 * 4096 * 64;  // 4,194,304
  __bf16* q = (__bf16*)d_ws;
  __bf16* k = q + qelems;
  __bf16* vt = k + qelems;          // V transposed [bh][dh][s]
  __bf16* xb = vt + qelems;         // converted x; reused as ao
  __bf16* wqb = xb + qelems;        // converted w_qkv
  __bf16* wob = wqb + 1536 * 512;   // converted w_out
  __bf16* ao = xb;                  // attn out aliases xb

  // Stage 0: fp32 -> bf16
  cvt_f32_bf16<<<dim3((int)(qelems / 4 / 256)), dim3(256), 0, stream>>>(
      x, xb, (int)(qelems / 4));
  cvt_f32_bf16<<<dim3(768), dim3(256), 0, stream>>>(w_qkv, wqb, 1536 * 512 / 4);
  cvt_f32_bf16<<<dim3(256), dim3(256), 0, stream>>>(w_out, wob, 512 * 512 / 4);

  // Stage 1: QKV GEMM (v written transposed)
  gemm_bt<512, true><<<dim3(3072), dim3(256), 0, stream>>>(
      xb, wqb, q, k, vt, nullptr, 48);
  // Stage 2: MFMA attention: 16 bh * 64 tiles = 1024 workgroups
  attn_mfma<<<dim3(1024), dim3(256), 0, stream>>>(q, k, vt, ao);
  // Stage 3: out GEMM
  gemm_bt<512, false><<<dim3(1024), dim3(256), 0, stream>>>(
      ao, wob, nullptr, nullptr, nullptr, out, 16);
}

// Round 5
// 156.148 us; speedup vs baseline: 2.4259x; 1.5294x over previous
//
#include <hip/hip_runtime.h>
#include <hip/hip_bf16.h>

// NeighbourhoodAttnBlock: B=2, H=W=64, D=512, NH=8, DH=64, KERNEL=7
// Inputs fp32; output fp32. Internal pipeline bf16 MFMA.
// Stage 0: convert x, w_qkv, w_out fp32 -> bf16 in ws
// Stage 1: qkv GEMM (m97-style LDS-staged) -> q,k [bh][s][dh]; vt [bh][dh][s]
// Stage 2: MFMA neighbourhood attention, one workgroup per (bh, 8x8 query tile)
// Stage 3: out GEMM (LDS-staged) -> d_out (fp32)

typedef __bf16 bf16x8 __attribute__((ext_vector_type(8)));
typedef __bf16 bf16x4 __attribute__((ext_vector_type(4)));
typedef float  f32x4  __attribute__((ext_vector_type(4)));

__global__ __launch_bounds__(256) void cvt_f32_bf16(
    const float* __restrict__ src, __bf16* __restrict__ dst, int n4) {
  int i = blockIdx.x * blockDim.x + threadIdx.x;
  if (i < n4) {
    f32x4 v = ((const f32x4*)src)[i];
    bf16x4 o;
    o[0] = (__bf16)v[0]; o[1] = (__bf16)v[1];
    o[2] = (__bf16)v[2]; o[3] = (__bf16)v[3];
    ((bf16x4*)dst)[i] = o;
  }
}

__device__ __forceinline__ void gload_lds16(const __bf16* g, __bf16* l) {
  // async global->LDS, 16B/lane; LDS dst = wave-uniform base + lane*16
  __builtin_amdgcn_global_load_lds(
      (const __attribute__((address_space(1))) void*)g,
      (__attribute__((address_space(3))) void*)l, 16, 0, 0);
}

// C[i][e] = sum_d A[i][d] * W[e][d];  A:[M,512], W:[E,512] row-major bf16.
// 128x128 block tile, 4 waves x (64x64), BK=32, global_load_lds staging.
// A/B frag [m|n=lane&15][k=(lane>>4)*8+j]; C/D: col(n)=lane&15,
// row(m)=(lane>>4)*4+reg.
template <bool QKV>
__global__ __launch_bounds__(256, 3) void gemm_lds(
    const __bf16* __restrict__ A, const __bf16* __restrict__ W,
    __bf16* __restrict__ qo, __bf16* __restrict__ ko, __bf16* __restrict__ vo,
    float* __restrict__ co, int etiles) {
  constexpr int K = 512;
  __shared__ alignas(16) __bf16 Al[128 * 32];
  __shared__ alignas(16) __bf16 Wl[128 * 32];
  const int tid = threadIdx.x;
  const int wv = tid >> 6, lane = tid & 63;
  const int n16 = lane & 15, quad = lane >> 4;
  const int bi = blockIdx.x / etiles, be = blockIdx.x % etiles;
  const int i0 = bi << 7, e0 = be << 7;
  const int wm = (wv & 1) << 6, we = (wv >> 1) << 6;  // wave's 64x64 sub-tile

  // staging: thread covers row wv*16 + lane/4 (+64 for round 1), 8-elem seg lane&3
  const int srow = (wv << 4) + (lane >> 2);
  const int scol = (lane & 3) << 3;
  const __bf16* gA = A + (size_t)(i0 + srow) * K + scol;
  const __bf16* gW = W + (size_t)(e0 + srow) * K + scol;
  __bf16* lA = &Al[(wv << 9) + (lane << 3)];  // == (row*32 + seg*8)
  __bf16* lW = &Wl[(wv << 9) + (lane << 3)];

  f32x4 acc[4][4];
#pragma unroll
  for (int a = 0; a < 4; ++a)
#pragma unroll
    for (int b = 0; b < 4; ++b) acc[a][b] = (f32x4){0.f, 0.f, 0.f, 0.f};

  for (int k0 = 0; k0 < K; k0 += 32) {
    if (k0) __syncthreads();  // previous iter's LDS reads must finish
    gload_lds16(gA + k0, lA);
    gload_lds16(gA + (size_t)64 * K + k0, lA + 64 * 32);
    gload_lds16(gW + k0, lW);
    gload_lds16(gW + (size_t)64 * K + k0, lW + 64 * 32);
    __syncthreads();  // drains vmcnt -> staging visible

    bf16x8 af[4], wf[4];
#pragma unroll
    for (int t = 0; t < 4; ++t) {
      af[t] = *(const bf16x8*)&Al[(wm + t * 16 + n16) * 32 + quad * 8];
      wf[t] = *(const bf16x8*)&Wl[(we + t * 16 + n16) * 32 + quad * 8];
    }
#pragma unroll
    for (int mt = 0; mt < 4; ++mt)
#pragma unroll
      for (int nt = 0; nt < 4; ++nt)
        acc[mt][nt] =
            __builtin_amdgcn_mfma_f32_16x16x32_bf16(af[mt], wf[nt], acc[mt][nt], 0, 0, 0);
  }

  // epilogue
#pragma unroll
  for (int mt = 0; mt < 4; ++mt)
#pragma unroll
    for (int nt = 0; nt < 4; ++nt) {
      f32x4 f = acc[mt][nt];
      int e = e0 + we + nt * 16 + n16;
#pragma unroll
      for (int rg = 0; rg < 4; ++rg) {
        int i = i0 + wm + mt * 16 + quad * 4 + rg;
        float val = f[rg];
        if (QKV) {
          int t = e >> 9, head = (e >> 6) & 7, dh = e & 63;
          int b = i >> 12, s = i & 4095;
          int bh = b * 8 + head;
          if (t == 2) {
            vo[((size_t)bh * 64 + dh) * 4096 + s] = (__bf16)val;  // vt[bh][dh][s]
          } else {
            size_t off = (((size_t)bh * 4096) + s) * 64 + dh;
            ((t == 0) ? qo : ko)[off] = (__bf16)val;
          }
        } else {
          co[(size_t)i * 512 + e] = val;  // fp32 output
        }
      }
    }
}

// MFMA neighbourhood attention. One workgroup per (bh, 8x8 query tile).
// Wave wv handles queries [wv*16, wv*16+16). Key window: 14 rows x 16 cols
// (wc0 multiple of 4), 224 keys; invalid keys masked exactly per query.
__global__ __launch_bounds__(256) void attn_mfma(
    const __bf16* __restrict__ q, const __bf16* __restrict__ k,
    const __bf16* __restrict__ vt, __bf16* __restrict__ out) {
  __shared__ alignas(16) __bf16 plds[4][16][232];  // per-wave P, +8 pad
  const int wv = threadIdx.x >> 6;
  const int lane = threadIdx.x & 63;
  const int n16 = lane & 15, quad = lane >> 4;
  const int bh = blockIdx.x >> 6;
  const int tile = blockIdx.x & 63;
  const int qh0 = (tile >> 3) << 3, qw0 = (tile & 7) << 3;
  int wh0 = qh0 - 3; wh0 = wh0 < 0 ? 0 : (wh0 > 50 ? 50 : wh0);
  int wc0 = qw0 - 3; wc0 = wc0 < 0 ? 0 : (wc0 > 48 ? 48 : wc0);
  wc0 &= ~1;  // -> multiple of 4 here; covers [qw0-3, qw0+10]
  const size_t base = (size_t)bh * 4096 * 64;

  const int qi_a = wv * 16 + n16;
  const int sqa = (qh0 + (qi_a >> 3)) * 64 + qw0 + (qi_a & 7);
  const __bf16* qp = q + base + (size_t)sqa * 64 + quad * 8;
  bf16x8 aq0 = *(const bf16x8*)qp;
  bf16x8 aq1 = *(const bf16x8*)(qp + 32);

  f32x4 S[14];
  const int skw = wc0 + n16;
#pragma unroll
  for (int nt = 0; nt < 14; ++nt) {
    const __bf16* kp =
        k + base + (size_t)((wh0 + nt) * 64 + skw) * 64 + quad * 8;
    bf16x8 b0 = *(const bf16x8*)kp;
    bf16x8 b1 = *(const bf16x8*)(kp + 32);
    f32x4 s = {0.f, 0.f, 0.f, 0.f};
    s = __builtin_amdgcn_mfma_f32_16x16x32_bf16(aq0, b0, s, 0, 0, 0);
    s = __builtin_amdgcn_mfma_f32_16x16x32_bf16(aq1, b1, s, 0, 0, 0);
    S[nt] = s;
  }

  float mx[4] = {-1e30f, -1e30f, -1e30f, -1e30f};
#pragma unroll
  for (int reg = 0; reg < 4; ++reg) {
    int qi = wv * 16 + quad * 4 + reg;
    int qh = qh0 + (qi >> 3), qw = qw0 + (qi & 7);
    int sh = qh - 3; sh = sh < 0 ? 0 : (sh > 57 ? 57 : sh);
    int sw = qw - 3; sw = sw < 0 ? 0 : (sw > 57 ? 57 : sw);
    bool wok = (skw >= sw) && (skw < sw + 7);
#pragma unroll
    for (int nt = 0; nt < 14; ++nt) {
      int kh = wh0 + nt;
      bool ok = wok && (kh >= sh) && (kh < sh + 7);
      float val = ok ? S[nt][reg] * 0.125f : -1e30f;
      S[nt][reg] = val;
      mx[reg] = mx[reg] > val ? mx[reg] : val;
    }
  }
#pragma unroll
  for (int reg = 0; reg < 4; ++reg)
#pragma unroll
    for (int off = 8; off >= 1; off >>= 1) {
      float o = __shfl_xor(mx[reg], off);
      mx[reg] = mx[reg] > o ? mx[reg] : o;
    }

  float sm[4] = {0.f, 0.f, 0.f, 0.f};
#pragma unroll
  for (int nt = 0; nt < 14; ++nt)
#pragma unroll
    for (int reg = 0; reg < 4; ++reg) {
      float p = __expf(S[nt][reg] - mx[reg]);
      S[nt][reg] = p;
      sm[reg] += p;
    }
#pragma unroll
  for (int reg = 0; reg < 4; ++reg)
#pragma unroll
    for (int off = 8; off >= 1; off >>= 1) sm[reg] += __shfl_xor(sm[reg], off);

#pragma unroll
  for (int reg = 0; reg < 4; ++reg) {
    float inv = 1.f / sm[reg];
    int row = quad * 4 + reg;
#pragma unroll
    for (int nt = 0; nt < 14; ++nt)
      plds[wv][row][nt * 16 + n16] = (__bf16)(S[nt][reg] * inv);
  }

  f32x4 O[4] = {{0.f, 0.f, 0.f, 0.f},
                {0.f, 0.f, 0.f, 0.f},
                {0.f, 0.f, 0.f, 0.f},
                {0.f, 0.f, 0.f, 0.f}};
#pragma unroll
  for (int kt = 0; kt < 7; ++kt) {
    bf16x8 pa = *(const bf16x8*)&plds[wv][n16][kt * 32 + quad * 8];
    int key0 = kt * 32 + quad * 8;
    int sv = (wh0 + (key0 >> 4)) * 64 + wc0 + (key0 & 15);
#pragma unroll
    for (int ntv = 0; ntv < 4; ++ntv) {
      const __bf16* vp = vt + base + (size_t)(ntv * 16 + n16) * 4096 + sv;
      union { bf16x8 v8; bf16x4 v4[2]; } u;
      u.v4[0] = *(const bf16x4*)vp;
      u.v4[1] = *(const bf16x4*)(vp + 4);
      O[ntv] = __builtin_amdgcn_mfma_f32_16x16x32_bf16(pa, u.v8, O[ntv], 0, 0, 0);
    }
  }

  const int b = bh >> 3, head = bh & 7;
#pragma unroll
  for (int ntv = 0; ntv < 4; ++ntv)
#pragma unroll
    for (int reg = 0; reg < 4; ++reg) {
      int qi = wv * 16 + quad * 4 + reg;
      int s_q = (qh0 + (qi >> 3)) * 64 + qw0 + (qi & 7);
      int dh = ntv * 16 + n16;
      out[((size_t)(b * 4096 + s_q)) * 512 + head * 64 + dh] =
          (__bf16)O[ntv][reg];
    }
}

extern "C" void kernel_launch(void* const* d_in, const int* in_sizes, int n_in,
                              void* d_out, int out_size, void* d_ws,
                              size_t ws_size, hipStream_t stream) {
  const float* x = (const float*)d_in[0];      // [2,64,64,512] fp32
  const float* w_qkv = (const float*)d_in[1];  // [1536,512] fp32
  const float* w_out = (const float*)d_in[2];  // [512,512] fp32
  float* out = (float*)d_out;                  // [2,64,64,512] fp32

  const size_t qelems = (size_t)2 * 8 * 4096 * 64;  // 4,194,304
  __bf16* q = (__bf16*)d_ws;
  __bf16* k = q + qelems;
  __bf16* vt = k + qelems;          // V transposed [bh][dh][s]
  __bf16* xb = vt + qelems;         // converted x; reused as ao
  __bf16* wqb = xb + qelems;        // converted w_qkv
  __bf16* wob = wqb + 1536 * 512;   // converted w_out
  __bf16* ao = xb;                  // attn out aliases xb

  // Stage 0: fp32 -> bf16
  cvt_f32_bf16<<<dim3((int)(qelems / 4 / 256)), dim3(256), 0, stream>>>(
      x, xb, (int)(qelems / 4));
  cvt_f32_bf16<<<dim3(768), dim3(256), 0, stream>>>(w_qkv, wqb, 1536 * 512 / 4);
  cvt_f32_bf16<<<dim3(256), dim3(256), 0, stream>>>(w_out, wob, 512 * 512 / 4);

  // Stage 1: QKV GEMM: 64 i-tiles x 12 e-tiles = 768 blocks (3/CU)
  gemm_lds<true><<<dim3(768), dim3(256), 0, stream>>>(
      xb, wqb, q, k, vt, nullptr, 12);
  // Stage 2: MFMA attention: 16 bh * 64 tiles = 1024 workgroups
  attn_mfma<<<dim3(1024), dim3(256), 0, stream>>>(q, k, vt, ao);
  // Stage 3: out GEMM: 64 x 4 = 256 blocks
  gemm_lds<false><<<dim3(256), dim3(256), 0, stream>>>(
      ao, wob, nullptr, nullptr, nullptr, out, 4);
}

// Round 6
// 139.896 us; speedup vs baseline: 2.7078x; 1.1162x over previous
//
#include <hip/hip_runtime.h>
#include <hip/hip_bf16.h>

// NeighbourhoodAttnBlock: B=2, H=W=64, D=512, NH=8, DH=64, KERNEL=7
// Inputs fp32; output fp32. Internal pipeline bf16 MFMA.
// Stage 0: fused convert x, w_qkv, w_out fp32 -> bf16 in ws
// Stage 1: qkv GEMM (LDS-staged) -> q,k [bh][s][dh]; vt [bh][dh][s]
// Stage 2: MFMA neighbourhood attention, K-window staged in LDS (phase-shared
//          with the P buffer), one workgroup per (bh, 8x8 query tile)
// Stage 3: out GEMM (LDS-staged, BN=64 for 2 blocks/CU) -> d_out (fp32)

typedef __bf16 bf16x8 __attribute__((ext_vector_type(8)));
typedef __bf16 bf16x4 __attribute__((ext_vector_type(4)));
typedef float  f32x4  __attribute__((ext_vector_type(4)));

__global__ __launch_bounds__(256) void cvt_all(
    const float* __restrict__ x, const float* __restrict__ wq,
    const float* __restrict__ wo, __bf16* __restrict__ xb,
    __bf16* __restrict__ wqb, __bf16* __restrict__ wob) {
  int i = blockIdx.x * 256 + threadIdx.x;  // 1310720 total f32x4 chunks
  const float* src;
  __bf16* dst;
  int j = i;
  if (j < 1048576) {
    src = x; dst = xb;
  } else if (j < 1048576 + 196608) {
    j -= 1048576; src = wq; dst = wqb;
  } else {
    j -= 1048576 + 196608; src = wo; dst = wob;
  }
  f32x4 v = ((const f32x4*)src)[j];
  bf16x4 o;
  o[0] = (__bf16)v[0]; o[1] = (__bf16)v[1];
  o[2] = (__bf16)v[2]; o[3] = (__bf16)v[3];
  ((bf16x4*)dst)[j] = o;
}

__device__ __forceinline__ void gload_lds16(const __bf16* g, __bf16* l) {
  __builtin_amdgcn_global_load_lds(
      (const __attribute__((address_space(1))) void*)g,
      (__attribute__((address_space(3))) void*)l, 16, 0, 0);
}

// C[i][e] = sum_d A[i][d] * W[e][d];  A:[M,512], W:[E,512] row-major bf16.
// 128xBN block tile, 4 waves x (64 x BN/2), BK=32, global_load_lds staging.
// A/B frag [m|n=lane&15][k=(lane>>4)*8+j]; C/D: col(n)=lane&15,
// row(m)=(lane>>4)*4+reg.
template <bool QKV, int BN>
__global__ __launch_bounds__(256, 3) void gemm_lds(
    const __bf16* __restrict__ A, const __bf16* __restrict__ W,
    __bf16* __restrict__ qo, __bf16* __restrict__ ko, __bf16* __restrict__ vo,
    float* __restrict__ co, int etiles) {
  constexpr int K = 512;
  constexpr int NT = BN / 32;  // W-frags / accs per wave in e-dim
  __shared__ alignas(16) __bf16 Al[128 * 32];
  __shared__ alignas(16) __bf16 Wl[BN * 32];
  const int tid = threadIdx.x;
  const int wv = tid >> 6, lane = tid & 63;
  const int n16 = lane & 15, quad = lane >> 4;
  const int bi = blockIdx.x / etiles, be = blockIdx.x % etiles;
  const int i0 = bi << 7, e0 = be * BN;
  const int wm = (wv & 1) << 6, we = (wv >> 1) * (BN / 2);

  const int srow = (wv << 4) + (lane >> 2);  // 0..63
  const int scol = (lane & 3) << 3;
  const __bf16* gA = A + (size_t)(i0 + srow) * K + scol;
  const __bf16* gW = W + (size_t)(e0 + srow) * K + scol;
  __bf16* lA = &Al[(wv << 9) + (lane << 3)];
  __bf16* lW = &Wl[(wv << 9) + (lane << 3)];

  f32x4 acc[4][NT];
#pragma unroll
  for (int a = 0; a < 4; ++a)
#pragma unroll
    for (int b = 0; b < NT; ++b) acc[a][b] = (f32x4){0.f, 0.f, 0.f, 0.f};

  for (int k0 = 0; k0 < K; k0 += 32) {
    if (k0) __syncthreads();
    gload_lds16(gA + k0, lA);
    gload_lds16(gA + (size_t)64 * K + k0, lA + 64 * 32);
    gload_lds16(gW + k0, lW);
    if (BN == 128) gload_lds16(gW + (size_t)64 * K + k0, lW + 64 * 32);
    __syncthreads();

    bf16x8 af[4], wf[NT];
#pragma unroll
    for (int t = 0; t < 4; ++t)
      af[t] = *(const bf16x8*)&Al[(wm + t * 16 + n16) * 32 + quad * 8];
#pragma unroll
    for (int t = 0; t < NT; ++t)
      wf[t] = *(const bf16x8*)&Wl[(we + t * 16 + n16) * 32 + quad * 8];
#pragma unroll
    for (int mt = 0; mt < 4; ++mt)
#pragma unroll
      for (int nt = 0; nt < NT; ++nt)
        acc[mt][nt] = __builtin_amdgcn_mfma_f32_16x16x32_bf16(
            af[mt], wf[nt], acc[mt][nt], 0, 0, 0);
  }

#pragma unroll
  for (int mt = 0; mt < 4; ++mt)
#pragma unroll
    for (int nt = 0; nt < NT; ++nt) {
      f32x4 f = acc[mt][nt];
      int e = e0 + we + nt * 16 + n16;
#pragma unroll
      for (int rg = 0; rg < 4; ++rg) {
        int i = i0 + wm + mt * 16 + quad * 4 + rg;
        float val = f[rg];
        if (QKV) {
          int t = e >> 9, head = (e >> 6) & 7, dh = e & 63;
          int b = i >> 12, s = i & 4095;
          int bh = b * 8 + head;
          if (t == 2) {
            vo[((size_t)bh * 64 + dh) * 4096 + s] = (__bf16)val;  // vt[bh][dh][s]
          } else {
            size_t off = (((size_t)bh * 4096) + s) * 64 + dh;
            ((t == 0) ? qo : ko)[off] = (__bf16)val;
          }
        } else {
          co[(size_t)i * 512 + e] = val;  // fp32 output
        }
      }
    }
}

// MFMA neighbourhood attention. One workgroup per (bh, 8x8 query tile).
// Phase 1: coop-load K-window (14x16 keys x 64 dh, xor-swizzled dh segments)
// into sbuf; QK^T B-frags via ds_read_b128. Phase 2 (after barrier): sbuf
// becomes per-wave P storage; PV with V direct from global (vt layout).
__global__ __launch_bounds__(256) void attn_mfma(
    const __bf16* __restrict__ q, const __bf16* __restrict__ k,
    const __bf16* __restrict__ vt, __bf16* __restrict__ out) {
  __shared__ alignas(16) __bf16 sbuf[4][16][232];  // 29696 B; kwin needs 28672
  __bf16* kwin = &sbuf[0][0][0];
  const int tid = threadIdx.x;
  const int wv = tid >> 6;
  const int lane = tid & 63;
  const int n16 = lane & 15, quad = lane >> 4;
  const int bh = blockIdx.x >> 6;
  const int tile = blockIdx.x & 63;
  const int qh0 = (tile >> 3) << 3, qw0 = (tile & 7) << 3;
  int wh0 = qh0 - 3; wh0 = wh0 < 0 ? 0 : (wh0 > 50 ? 50 : wh0);
  int wc0 = qw0 - 3; wc0 = wc0 < 0 ? 0 : (wc0 > 48 ? 48 : wc0);
  wc0 &= ~1;  // multiple of 4 in practice; covers [qw0-3, qw0+10]
  const size_t base = (size_t)bh * 4096 * 64;

  // ---- Q A-frags (global, issue first so they fly during coop load) ----
  const int qi_a = wv * 16 + n16;
  const int sqa = (qh0 + (qi_a >> 3)) * 64 + qw0 + (qi_a & 7);
  const __bf16* qp = q + base + (size_t)sqa * 64 + quad * 8;
  bf16x8 aq0 = *(const bf16x8*)qp;
  bf16x8 aq1 = *(const bf16x8*)(qp + 32);

  // ---- coop load K window: 14 rows x 2 KB contiguous each ----
  const __bf16* kbase = k + base;
#pragma unroll
  for (int i = 0; i < 7; ++i) {
    int ch = i * 256 + tid;           // 0..1791 16-B chunks
    int kr = ch >> 7, wi = ch & 127;  // wi = kc*8 + dh8
    int kc = wi >> 3, dh8 = wi & 7;
    bf16x8 d = *(const bf16x8*)(kbase +
        (size_t)((wh0 + kr) * 64 + wc0 + kc) * 64 + dh8 * 8);
    *(bf16x8*)&kwin[(kr * 16 + kc) * 64 + ((dh8 ^ (kc & 7)) * 8)] = d;
  }
  __syncthreads();

  // ---- scores from LDS: S[nt] = Q . K_row(nt)^T ----
  f32x4 S[14];
  const int skw = wc0 + n16;
  const int sw1 = ((quad ^ (n16 & 7)) * 8);
  const int sw2 = (((4 + quad) ^ (n16 & 7)) * 8);
#pragma unroll
  for (int nt = 0; nt < 14; ++nt) {
    int key = nt * 16 + n16;
    bf16x8 b0 = *(const bf16x8*)&kwin[key * 64 + sw1];
    bf16x8 b1 = *(const bf16x8*)&kwin[key * 64 + sw2];
    f32x4 s = {0.f, 0.f, 0.f, 0.f};
    s = __builtin_amdgcn_mfma_f32_16x16x32_bf16(aq0, b0, s, 0, 0, 0);
    s = __builtin_amdgcn_mfma_f32_16x16x32_bf16(aq1, b1, s, 0, 0, 0);
    S[nt] = s;
  }

  // ---- exact mask + scale + row max ----
  float mx[4] = {-1e30f, -1e30f, -1e30f, -1e30f};
#pragma unroll
  for (int reg = 0; reg < 4; ++reg) {
    int qi = wv * 16 + quad * 4 + reg;
    int qh = qh0 + (qi >> 3), qw = qw0 + (qi & 7);
    int sh = qh - 3; sh = sh < 0 ? 0 : (sh > 57 ? 57 : sh);
    int sw = qw - 3; sw = sw < 0 ? 0 : (sw > 57 ? 57 : sw);
    bool wok = (skw >= sw) && (skw < sw + 7);
#pragma unroll
    for (int nt = 0; nt < 14; ++nt) {
      int kh = wh0 + nt;
      bool ok = wok && (kh >= sh) && (kh < sh + 7);
      float val = ok ? S[nt][reg] * 0.125f : -1e30f;
      S[nt][reg] = val;
      mx[reg] = mx[reg] > val ? mx[reg] : val;
    }
  }
#pragma unroll
  for (int reg = 0; reg < 4; ++reg)
#pragma unroll
    for (int off = 8; off >= 1; off >>= 1) {
      float o = __shfl_xor(mx[reg], off);
      mx[reg] = mx[reg] > o ? mx[reg] : o;
    }

  // ---- exp + row sum ----
  float sm[4] = {0.f, 0.f, 0.f, 0.f};
#pragma unroll
  for (int nt = 0; nt < 14; ++nt)
#pragma unroll
    for (int reg = 0; reg < 4; ++reg) {
      float p = __expf(S[nt][reg] - mx[reg]);
      S[nt][reg] = p;
      sm[reg] += p;
    }
#pragma unroll
  for (int reg = 0; reg < 4; ++reg)
#pragma unroll
    for (int off = 8; off >= 1; off >>= 1) sm[reg] += __shfl_xor(sm[reg], off);

  __syncthreads();  // all waves done reading kwin; sbuf becomes P storage

  // ---- P -> LDS (bf16, C-layout scatter), per-wave region ----
#pragma unroll
  for (int reg = 0; reg < 4; ++reg) {
    float inv = 1.f / sm[reg];
    int row = quad * 4 + reg;
#pragma unroll
    for (int nt = 0; nt < 14; ++nt)
      sbuf[wv][row][nt * 16 + n16] = (__bf16)(S[nt][reg] * inv);
  }

  // ---- PV: O[16q x 64dh] = P(16x224) . V_win(224x64), V from global ----
  f32x4 O[4] = {{0.f, 0.f, 0.f, 0.f},
                {0.f, 0.f, 0.f, 0.f},
                {0.f, 0.f, 0.f, 0.f},
                {0.f, 0.f, 0.f, 0.f}};
#pragma unroll
  for (int kt = 0; kt < 7; ++kt) {
    bf16x8 pa = *(const bf16x8*)&sbuf[wv][n16][kt * 32 + quad * 8];
    int key0 = kt * 32 + quad * 8;
    int sv = (wh0 + (key0 >> 4)) * 64 + wc0 + (key0 & 15);
#pragma unroll
    for (int ntv = 0; ntv < 4; ++ntv) {
      const __bf16* vp = vt + base + (size_t)(ntv * 16 + n16) * 4096 + sv;
      union { bf16x8 v8; bf16x4 v4[2]; } u;
      u.v4[0] = *(const bf16x4*)vp;
      u.v4[1] = *(const bf16x4*)(vp + 4);
      O[ntv] = __builtin_amdgcn_mfma_f32_16x16x32_bf16(pa, u.v8, O[ntv], 0, 0, 0);
    }
  }

  // ---- epilogue: ao[b][s][head*64+dh] bf16 ----
  const int b = bh >> 3, head = bh & 7;
#pragma unroll
  for (int ntv = 0; ntv < 4; ++ntv)
#pragma unroll
    for (int reg = 0; reg < 4; ++reg) {
      int qi = wv * 16 + quad * 4 + reg;
      int s_q = (qh0 + (qi >> 3)) * 64 + qw0 + (qi & 7);
      int dh = ntv * 16 + n16;
      out[((size_t)(b * 4096 + s_q)) * 512 + head * 64 + dh] =
          (__bf16)O[ntv][reg];
    }
}

extern "C" void kernel_launch(void* const* d_in, const int* in_sizes, int n_in,
                              void* d_out, int out_size, void* d_ws,
                              size_t ws_size, hipStream_t stream) {
  const float* x = (const float*)d_in[0];      // [2,64,64,512] fp32
  const float* w_qkv = (const float*)d_in[1];  // [1536,512] fp32
  const float* w_out = (const float*)d_in[2];  // [512,512] fp32
  float* out = (float*)d_out;                  // [2,64,64,512] fp32

  const size_t qelems = (size_t)2 * 8 * 4096 * 64;  // 4,194,304
  __bf16* q = (__bf16*)d_ws;
  __bf16* k = q + qelems;
  __bf16* vt = k + qelems;          // V transposed [bh][dh][s]
  __bf16* xb = vt + qelems;         // converted x; reused as ao
  __bf16* wqb = xb + qelems;        // converted w_qkv
  __bf16* wob = wqb + 1536 * 512;   // converted w_out
  __bf16* ao = xb;                  // attn out aliases xb

  // Stage 0: fused fp32 -> bf16 (x: 1048576, wq: 196608, wo: 65536 f32x4)
  cvt_all<<<dim3(5120), dim3(256), 0, stream>>>(x, w_qkv, w_out, xb, wqb, wob);

  // Stage 1: QKV GEMM: 64 i-tiles x 12 e-tiles = 768 blocks (3/CU)
  gemm_lds<true, 128><<<dim3(768), dim3(256), 0, stream>>>(
      xb, wqb, q, k, vt, nullptr, 12);
  // Stage 2: MFMA attention: 16 bh * 64 tiles = 1024 workgroups
  attn_mfma<<<dim3(1024), dim3(256), 0, stream>>>(q, k, vt, ao);
  // Stage 3: out GEMM: 64 i-tiles x 8 e-tiles = 512 blocks (2/CU)
  gemm_lds<false, 64><<<dim3(512), dim3(256), 0, stream>>>(
      ao, wob, nullptr, nullptr, nullptr, out, 8);
}

// Round 7
// 137.254 us; speedup vs baseline: 2.7599x; 1.0192x over previous
//
#include <hip/hip_runtime.h>
#include <hip/hip_bf16.h>

// NeighbourhoodAttnBlock: B=2, H=W=64, D=512, NH=8, DH=64, KERNEL=7
// Inputs fp32; output fp32. Internal pipeline bf16 MFMA.
// Stage 0: fused convert x, w_qkv, w_out fp32 -> bf16 in ws
// Stage 1: qkv GEMM (LDS-staged) -> q,k [bh][s][dh]; vt [bh][dh][s]
// Stage 2: MFMA neighbourhood attention; K-window AND V-window staged in LDS
// Stage 3: out GEMM (LDS-staged, BN=64) -> d_out (fp32)

typedef __bf16 bf16x8 __attribute__((ext_vector_type(8)));
typedef __bf16 bf16x4 __attribute__((ext_vector_type(4)));
typedef float  f32x4  __attribute__((ext_vector_type(4)));

__global__ __launch_bounds__(256) void cvt_all(
    const float* __restrict__ x, const float* __restrict__ wq,
    const float* __restrict__ wo, __bf16* __restrict__ xb,
    __bf16* __restrict__ wqb, __bf16* __restrict__ wob) {
  int i = blockIdx.x * 256 + threadIdx.x;  // 1310720 total f32x4 chunks
  const float* src;
  __bf16* dst;
  int j = i;
  if (j < 1048576) {
    src = x; dst = xb;
  } else if (j < 1048576 + 196608) {
    j -= 1048576; src = wq; dst = wqb;
  } else {
    j -= 1048576 + 196608; src = wo; dst = wob;
  }
  f32x4 v = ((const f32x4*)src)[j];
  bf16x4 o;
  o[0] = (__bf16)v[0]; o[1] = (__bf16)v[1];
  o[2] = (__bf16)v[2]; o[3] = (__bf16)v[3];
  ((bf16x4*)dst)[j] = o;
}

__device__ __forceinline__ void gload_lds16(const __bf16* g, __bf16* l) {
  __builtin_amdgcn_global_load_lds(
      (const __attribute__((address_space(1))) void*)g,
      (__attribute__((address_space(3))) void*)l, 16, 0, 0);
}

// C[i][e] = sum_d A[i][d] * W[e][d];  A:[M,512], W:[E,512] row-major bf16.
// 128xBN block tile, 4 waves x (64 x BN/2), BK=32, global_load_lds staging.
template <bool QKV, int BN>
__global__ __launch_bounds__(256, 3) void gemm_lds(
    const __bf16* __restrict__ A, const __bf16* __restrict__ W,
    __bf16* __restrict__ qo, __bf16* __restrict__ ko, __bf16* __restrict__ vo,
    float* __restrict__ co, int etiles) {
  constexpr int K = 512;
  constexpr int NT = BN / 32;
  __shared__ alignas(16) __bf16 Al[128 * 32];
  __shared__ alignas(16) __bf16 Wl[BN * 32];
  const int tid = threadIdx.x;
  const int wv = tid >> 6, lane = tid & 63;
  const int n16 = lane & 15, quad = lane >> 4;
  const int bi = blockIdx.x / etiles, be = blockIdx.x % etiles;
  const int i0 = bi << 7, e0 = be * BN;
  const int wm = (wv & 1) << 6, we = (wv >> 1) * (BN / 2);

  const int srow = (wv << 4) + (lane >> 2);
  const int scol = (lane & 3) << 3;
  const __bf16* gA = A + (size_t)(i0 + srow) * K + scol;
  const __bf16* gW = W + (size_t)(e0 + srow) * K + scol;
  __bf16* lA = &Al[(wv << 9) + (lane << 3)];
  __bf16* lW = &Wl[(wv << 9) + (lane << 3)];

  f32x4 acc[4][NT];
#pragma unroll
  for (int a = 0; a < 4; ++a)
#pragma unroll
    for (int b = 0; b < NT; ++b) acc[a][b] = (f32x4){0.f, 0.f, 0.f, 0.f};

  for (int k0 = 0; k0 < K; k0 += 32) {
    if (k0) __syncthreads();
    gload_lds16(gA + k0, lA);
    gload_lds16(gA + (size_t)64 * K + k0, lA + 64 * 32);
    gload_lds16(gW + k0, lW);
    if (BN == 128) gload_lds16(gW + (size_t)64 * K + k0, lW + 64 * 32);
    __syncthreads();

    bf16x8 af[4], wf[NT];
#pragma unroll
    for (int t = 0; t < 4; ++t)
      af[t] = *(const bf16x8*)&Al[(wm + t * 16 + n16) * 32 + quad * 8];
#pragma unroll
    for (int t = 0; t < NT; ++t)
      wf[t] = *(const bf16x8*)&Wl[(we + t * 16 + n16) * 32 + quad * 8];
#pragma unroll
    for (int mt = 0; mt < 4; ++mt)
#pragma unroll
      for (int nt = 0; nt < NT; ++nt)
        acc[mt][nt] = __builtin_amdgcn_mfma_f32_16x16x32_bf16(
            af[mt], wf[nt], acc[mt][nt], 0, 0, 0);
  }

#pragma unroll
  for (int mt = 0; mt < 4; ++mt)
#pragma unroll
    for (int nt = 0; nt < NT; ++nt) {
      f32x4 f = acc[mt][nt];
      int e = e0 + we + nt * 16 + n16;
#pragma unroll
      for (int rg = 0; rg < 4; ++rg) {
        int i = i0 + wm + mt * 16 + quad * 4 + rg;
        float val = f[rg];
        if (QKV) {
          int t = e >> 9, head = (e >> 6) & 7, dh = e & 63;
          int b = i >> 12, s = i & 4095;
          int bh = b * 8 + head;
          if (t == 2) {
            vo[((size_t)bh * 64 + dh) * 4096 + s] = (__bf16)val;  // vt[bh][dh][s]
          } else {
            size_t off = (((size_t)bh * 4096) + s) * 64 + dh;
            ((t == 0) ? qo : ko)[off] = (__bf16)val;
          }
        } else {
          co[(size_t)i * 512 + e] = val;  // fp32 output
        }
      }
    }
}

// MFMA neighbourhood attention. One workgroup per (bh, 8x8 query tile).
// Phase 1: coop-load K-window (14x16 keys x 64 dh, xor-swizzled) into r1;
//          QK^T via ds_read_b128; softmax in regs; P -> per-wave sbuf region.
// Phase 2: barrier; coop-load V-window into r1 as vwin[dh][232]; PV fully
//          from LDS (stride 464 B == 20 words mod 32 -> conflict-free b128).
__global__ __launch_bounds__(256) void attn_mfma(
    const __bf16* __restrict__ q, const __bf16* __restrict__ k,
    const __bf16* __restrict__ vt, __bf16* __restrict__ out) {
  __shared__ alignas(16) __bf16 r1[14848];         // kwin (28672B) / vwin 64x232
  __shared__ alignas(16) __bf16 sbuf[4][16][232];  // per-wave P (padded)
  const int tid = threadIdx.x;
  const int wv = tid >> 6;
  const int lane = tid & 63;
  const int n16 = lane & 15, quad = lane >> 4;
  const int bh = blockIdx.x >> 6;
  const int tile = blockIdx.x & 63;
  const int qh0 = (tile >> 3) << 3, qw0 = (tile & 7) << 3;
  int wh0 = qh0 - 3; wh0 = wh0 < 0 ? 0 : (wh0 > 50 ? 50 : wh0);
  int wc0 = qw0 - 3; wc0 = wc0 < 0 ? 0 : (wc0 > 48 ? 48 : wc0);
  wc0 &= ~1;  // -> multiple of 4; window covers [qw0-3, qw0+10]
  const size_t base = (size_t)bh * 4096 * 64;

  // ---- Q A-frags (issue first; fly during coop K load) ----
  const int qi_a = wv * 16 + n16;
  const int sqa = (qh0 + (qi_a >> 3)) * 64 + qw0 + (qi_a & 7);
  const __bf16* qp = q + base + (size_t)sqa * 64 + quad * 8;
  bf16x8 aq0 = *(const bf16x8*)qp;
  bf16x8 aq1 = *(const bf16x8*)(qp + 32);

  // ---- coop load K window: 14 rows x 2 KB contiguous each ----
  const __bf16* kbase = k + base;
#pragma unroll
  for (int i = 0; i < 7; ++i) {
    int ch = i * 256 + tid;           // 1792 16-B chunks
    int kr = ch >> 7, wi = ch & 127;
    int kc = wi >> 3, dh8 = wi & 7;
    bf16x8 d = *(const bf16x8*)(kbase +
        (size_t)((wh0 + kr) * 64 + wc0 + kc) * 64 + dh8 * 8);
    *(bf16x8*)&r1[(kr * 16 + kc) * 64 + ((dh8 ^ (kc & 7)) * 8)] = d;
  }
  __syncthreads();

  // ---- scores from LDS ----
  f32x4 S[14];
  const int skw = wc0 + n16;
  const int sw1 = ((quad ^ (n16 & 7)) * 8);
  const int sw2 = (((4 + quad) ^ (n16 & 7)) * 8);
#pragma unroll
  for (int nt = 0; nt < 14; ++nt) {
    int key = nt * 16 + n16;
    bf16x8 b0 = *(const bf16x8*)&r1[key * 64 + sw1];
    bf16x8 b1 = *(const bf16x8*)&r1[key * 64 + sw2];
    f32x4 s = {0.f, 0.f, 0.f, 0.f};
    s = __builtin_amdgcn_mfma_f32_16x16x32_bf16(aq0, b0, s, 0, 0, 0);
    s = __builtin_amdgcn_mfma_f32_16x16x32_bf16(aq1, b1, s, 0, 0, 0);
    S[nt] = s;
  }

  // ---- exact mask + scale + row max ----
  float mx[4] = {-1e30f, -1e30f, -1e30f, -1e30f};
#pragma unroll
  for (int reg = 0; reg < 4; ++reg) {
    int qi = wv * 16 + quad * 4 + reg;
    int qh = qh0 + (qi >> 3), qw = qw0 + (qi & 7);
    int sh = qh - 3; sh = sh < 0 ? 0 : (sh > 57 ? 57 : sh);
    int sw = qw - 3; sw = sw < 0 ? 0 : (sw > 57 ? 57 : sw);
    bool wok = (skw >= sw) && (skw < sw + 7);
#pragma unroll
    for (int nt = 0; nt < 14; ++nt) {
      int kh = wh0 + nt;
      bool ok = wok && (kh >= sh) && (kh < sh + 7);
      float val = ok ? S[nt][reg] * 0.125f : -1e30f;
      S[nt][reg] = val;
      mx[reg] = mx[reg] > val ? mx[reg] : val;
    }
  }
#pragma unroll
  for (int reg = 0; reg < 4; ++reg)
#pragma unroll
    for (int off = 8; off >= 1; off >>= 1) {
      float o = __shfl_xor(mx[reg], off);
      mx[reg] = mx[reg] > o ? mx[reg] : o;
    }

  // ---- exp + row sum ----
  float sm[4] = {0.f, 0.f, 0.f, 0.f};
#pragma unroll
  for (int nt = 0; nt < 14; ++nt)
#pragma unroll
    for (int reg = 0; reg < 4; ++reg) {
      float p = __expf(S[nt][reg] - mx[reg]);
      S[nt][reg] = p;
      sm[reg] += p;
    }
#pragma unroll
  for (int reg = 0; reg < 4; ++reg)
#pragma unroll
    for (int off = 8; off >= 1; off >>= 1) sm[reg] += __shfl_xor(sm[reg], off);

  // ---- P -> per-wave LDS region (wave-private; no barrier needed) ----
#pragma unroll
  for (int reg = 0; reg < 4; ++reg) {
    float inv = 1.f / sm[reg];
    int row = quad * 4 + reg;
#pragma unroll
    for (int nt = 0; nt < 14; ++nt)
      sbuf[wv][row][nt * 16 + n16] = (__bf16)(S[nt][reg] * inv);
  }

  __syncthreads();  // all waves done reading kwin
  // ---- coop load V window into vwin[dh][232] (key = kr*16+kc) ----
  const __bf16* vtb = vt + base;
#pragma unroll
  for (int i = 0; i < 7; ++i) {
    int c = i * 256 + tid;  // 1792 16-B chunks: c = dh*28 + kr*2 + half
    int dh = c / 28, rem = c % 28;
    int kr = rem >> 1, half = rem & 1;
    bf16x8 d = *(const bf16x8*)(vtb + (size_t)dh * 4096 +
                                (wh0 + kr) * 64 + wc0 + half * 8);
    *(bf16x8*)&r1[dh * 232 + kr * 16 + half * 8] = d;
  }
  __syncthreads();

  // ---- PV: O[16q x 64dh] = P(16x224) . V_win(224x64), all LDS ----
  f32x4 O[4] = {{0.f, 0.f, 0.f, 0.f},
                {0.f, 0.f, 0.f, 0.f},
                {0.f, 0.f, 0.f, 0.f},
                {0.f, 0.f, 0.f, 0.f}};
#pragma unroll
  for (int kt = 0; kt < 7; ++kt) {
    bf16x8 pa = *(const bf16x8*)&sbuf[wv][n16][kt * 32 + quad * 8];
    int key0 = kt * 32 + quad * 8;
#pragma unroll
    for (int ntv = 0; ntv < 4; ++ntv) {
      bf16x8 vb = *(const bf16x8*)&r1[(ntv * 16 + n16) * 232 + key0];
      O[ntv] = __builtin_amdgcn_mfma_f32_16x16x32_bf16(pa, vb, O[ntv], 0, 0, 0);
    }
  }

  // ---- epilogue: ao[b][s][head*64+dh] bf16 ----
  const int b = bh >> 3, head = bh & 7;
#pragma unroll
  for (int ntv = 0; ntv < 4; ++ntv)
#pragma unroll
    for (int reg = 0; reg < 4; ++reg) {
      int qi = wv * 16 + quad * 4 + reg;
      int s_q = (qh0 + (qi >> 3)) * 64 + qw0 + (qi & 7);
      int dh = ntv * 16 + n16;
      out[((size_t)(b * 4096 + s_q)) * 512 + head * 64 + dh] =
          (__bf16)O[ntv][reg];
    }
}

extern "C" void kernel_launch(void* const* d_in, const int* in_sizes, int n_in,
                              void* d_out, int out_size, void* d_ws,
                              size_t ws_size, hipStream_t stream) {
  const float* x = (const float*)d_in[0];      // [2,64,64,512] fp32
  const float* w_qkv = (const float*)d_in[1];  // [1536,512] fp32
  const float* w_out = (const float*)d_in[2];  // [512,512] fp32
  float* out = (float*)d_out;                  // [2,64,64,512] fp32

  const size_t qelems = (size_t)2 * 8 * 4096 * 64;  // 4,194,304
  __bf16* q = (__bf16*)d_ws;
  __bf16* k = q + qelems;
  __bf16* vt = k + qelems;          // V transposed [bh][dh][s]
  __bf16* xb = vt + qelems;         // converted x; reused as ao
  __bf16* wqb = xb + qelems;        // converted w_qkv
  __bf16* wob = wqb + 1536 * 512;   // converted w_out
  __bf16* ao = xb;                  // attn out aliases xb

  // Stage 0: fused fp32 -> bf16
  cvt_all<<<dim3(5120), dim3(256), 0, stream>>>(x, w_qkv, w_out, xb, wqb, wob);

  // Stage 1: QKV GEMM: 64 i-tiles x 12 e-tiles = 768 blocks (3/CU)
  gemm_lds<true, 128><<<dim3(768), dim3(256), 0, stream>>>(
      xb, wqb, q, k, vt, nullptr, 12);
  // Stage 2: MFMA attention: 16 bh * 64 tiles = 1024 workgroups
  attn_mfma<<<dim3(1024), dim3(256), 0, stream>>>(q, k, vt, ao);
  // Stage 3: out GEMM: 64 i-tiles x 8 e-tiles = 512 blocks (2/CU)
  gemm_lds<false, 64><<<dim3(512), dim3(256), 0, stream>>>(
      ao, wob, nullptr, nullptr, nullptr, out, 8);
}